// Round 2
// baseline (394.387 us; speedup 1.0000x reference)
//
#include <hip/hip_runtime.h>
#include <hip/hip_bf16.h>

#define T_TOKENS 16384
#define HIDDEN   2048
#define NEXP     64
#define TOPK     8
#define TOPKG    4
#define RSCALE   2.5f

#define TOKB     64                   // tokens per block (lane = token)
#define NBLK     (T_TOKENS / TOKB)    // 256 blocks
#define NWAVE    8                    // h-split across 8 waves
#define HW       (HIDDEN / NWAVE)     // 256 h per wave
#define CH       32                   // h per staging chunk
#define NCHW     (HW / CH)            // 8 chunks per wave
#define STRIDE_S 36                   // staged token row stride (floats, 16B-aligned, depadded banks)
#define SLAB_S   (TOKB * STRIDE_S)    // 2304 floats per wave slab
#define STRIDE_P 66                   // partial row stride (floats)
#define SLAB_P   (NEXP * STRIDE_P)    // 4224 floats per partial slab

// ---------------------------------------------------------------------------
// lane = token, acc[64] = logits for all experts over this wave's h-range.
// W reads are wave-uniform -> scalar loads (SMEM pipe); token reads come from
// per-wave private LDS slabs (1 ds_read_b128 feeds 256 FMAs).
// ---------------------------------------------------------------------------
__global__ __launch_bounds__(512)
void router_kernel(const float* __restrict__ tokens,
                   const float* __restrict__ W,
                   float* __restrict__ out,
                   float* __restrict__ wsP,
                   float* __restrict__ wsC,
                   int atomicMode)
{
    __shared__ float lds[NWAVE * SLAB_S];     // 18432 floats = 72 KB (aliased: staging, then partials)
    __shared__ float redP[NWAVE][NEXP];
    __shared__ float redC[NWAVE][NEXP];

    const int tid  = threadIdx.x;
    const int lane = tid & 63;
    const int wv   = __builtin_amdgcn_readfirstlane(tid >> 6);  // force wave-uniform
    const int base = blockIdx.x * TOKB;
    const int hbase = wv * HW;

    float acc[NEXP];
    #pragma unroll
    for (int e = 0; e < NEXP; ++e) acc[e] = 0.f;

    float* myStage = &lds[wv * SLAB_S];

    for (int c = 0; c < NCHW; ++c) {
        const int h0 = hbase + c * CH;
        // stage [64 tokens][32 h] into this wave's private slab (coalesced 128B runs)
        #pragma unroll
        for (int it = 0; it < 8; ++it) {
            int i  = it * 64 + lane;
            int t  = i >> 3;
            int j4 = i & 7;
            float4 v = *(const float4*)&tokens[(size_t)(base + t) * HIDDEN + h0 + j4 * 4];
            *(float4*)&myStage[t * STRIDE_S + j4 * 4] = v;
        }
        // no barrier needed: slab is wave-private; compiler inserts waitcnts
        #pragma unroll
        for (int h4 = 0; h4 < CH / 4; ++h4) {
            float4 t4 = *(const float4*)&myStage[lane * STRIDE_S + h4 * 4];
            #pragma unroll
            for (int e = 0; e < NEXP; ++e) {
                const float* wp = &W[(size_t)e * HIDDEN + h0 + h4 * 4];  // uniform -> s_load_dwordx4
                acc[e] = fmaf(wp[0], t4.x, acc[e]);
                acc[e] = fmaf(wp[1], t4.y, acc[e]);
                acc[e] = fmaf(wp[2], t4.z, acc[e]);
                acc[e] = fmaf(wp[3], t4.w, acc[e]);
            }
        }
    }
    __syncthreads();   // staging dead; LDS becomes partial slabs

    // deterministic cross-wave reduction: slab[w&3] = acc_w + acc_{w+4}
    {
        float* slab = &lds[(wv & 3) * SLAB_P];
        if (wv < 4) {
            #pragma unroll
            for (int e = 0; e < NEXP; ++e) slab[e * STRIDE_P + lane] = acc[e];
        }
        __syncthreads();
        if (wv >= 4) {
            #pragma unroll
            for (int e = 0; e < NEXP; ++e) slab[e * STRIDE_P + lane] += acc[e];
        }
        __syncthreads();
        // ((s0+s1)+s2)+s3 -> slab0  (fixed order, deterministic)
        for (int k = tid; k < NEXP * TOKB; k += 512) {
            int e = k >> 6, t = k & 63;
            int off = e * STRIDE_P + t;
            float s = ((lds[off] + lds[SLAB_P + off]) + lds[2 * SLAB_P + off]) + lds[3 * SLAB_P + off];
            lds[off] = s;
        }
        __syncthreads();
    }

    // ---- epilogue: wave wv handles tokens wv*8..wv*8+7, lane = expert ----
    float psum = 0.f;
    float cnt  = 0.f;

    #pragma unroll
    for (int tt = 0; tt < 8; ++tt) {
        const int tloc  = wv * 8 + tt;
        const int token = base + tloc;
        float logit = lds[lane * STRIDE_P + tloc];
        float s = 1.f / (1.f + expf(-logit));   // sigmoid, lane=expert

        // group max over 8 consecutive lanes
        float gm = s;
        gm = fmaxf(gm, __shfl_xor(gm, 1));
        gm = fmaxf(gm, __shfl_xor(gm, 2));
        gm = fmaxf(gm, __shfl_xor(gm, 4));

        // rank my group among the 8 group maxima (tie-break: lower index)
        const int myg = lane >> 3;
        int rank = 0;
        #pragma unroll
        for (int g = 0; g < 8; ++g) {
            float gs = __shfl(gm, g * 8);
            rank += (gs > gm) || (gs == gm && g < myg);
        }
        float routed = (rank < TOPKG) ? s : 0.f;

        // full-row score sum (aux normalization)
        float ssum = s;
        #pragma unroll
        for (int off = 1; off < 64; off <<= 1) ssum += __shfl_xor(ssum, off);
        psum += s / fmaxf(ssum, 1e-9f);

        // sequential top-8 wave argmax (value desc, lower index on ties)
        float v = routed;
        int   idx = lane;
        float denom = 0.f;
        float myv = 0.f;
        int   myi = 0;
        #pragma unroll
        for (int k = 0; k < TOPK; ++k) {
            float bv = v;
            int   bi = idx;
            #pragma unroll
            for (int off = 1; off < 64; off <<= 1) {
                float ov = __shfl_xor(bv, off);
                int   oi = __shfl_xor(bi, off);
                if (ov > bv || (ov == bv && oi < bi)) { bv = ov; bi = oi; }
            }
            denom += bv;
            if (lane == k) { myv = bv; myi = bi; }
            if (lane == bi) { v = -1.f; cnt += 1.f; }
        }
        float wscale = RSCALE / fmaxf(denom, 1e-9f);
        if (lane < TOPK) {
            out[(size_t)token * TOPK + lane] = (float)myi;
            out[(size_t)T_TOKENS * TOPK + (size_t)token * TOPK + lane] = myv * wscale;
        }
    }

    // ---- block-level reduction of aux stats ----
    redP[wv][lane] = psum;
    redC[wv][lane] = cnt;
    __syncthreads();
    if (tid < 64) {
        float p = 0.f, c = 0.f;
        #pragma unroll
        for (int w = 0; w < NWAVE; ++w) { p += redP[w][tid]; c += redC[w][tid]; }
        if (atomicMode) {
            atomicAdd(&wsP[tid], p);
            atomicAdd(&wsC[tid], c);
        } else {
            wsP[(size_t)blockIdx.x * 64 + tid] = p;
            wsC[(size_t)blockIdx.x * 64 + tid] = c;
        }
    }
}

// ---------------------------------------------------------------------------
// Kernel 2: reduce per-block stats -> aux loss scalar at out[T*K*2]
// ---------------------------------------------------------------------------
__global__ __launch_bounds__(256)
void aux_kernel(const float* __restrict__ wsP,
                const float* __restrict__ wsC,
                float* __restrict__ out, int nblk)
{
    __shared__ float sP[256];
    __shared__ float sC[256];
    const int tid  = threadIdx.x;
    const int e    = tid & 63;
    const int part = tid >> 6;
    float p = 0.f, c = 0.f;
    for (int b = part; b < nblk; b += 4) {
        p += wsP[(size_t)b * 64 + e];
        c += wsC[(size_t)b * 64 + e];
    }
    sP[tid] = p; sC[tid] = c;
    __syncthreads();
    if (tid < 64) {
        p = sP[tid] + sP[tid + 64] + sP[tid + 128] + sP[tid + 192];
        c = sC[tid] + sC[tid + 64] + sC[tid + 128] + sC[tid + 192];
        float val = (c * (1.f / ((float)T_TOKENS * (float)TOPK)))
                  * (p * (1.f / (float)T_TOKENS));
        #pragma unroll
        for (int off = 1; off < 64; off <<= 1) val += __shfl_xor(val, off);
        if (tid == 0) out[(size_t)T_TOKENS * TOPK * 2] = val * (float)NEXP;
    }
}

extern "C" void kernel_launch(void* const* d_in, const int* in_sizes, int n_in,
                              void* d_out, int out_size, void* d_ws, size_t ws_size,
                              hipStream_t stream)
{
    const float* tokens = (const float*)d_in[0];
    const float* W      = (const float*)d_in[1];
    float* out = (float*)d_out;

    const size_t needed = (size_t)NBLK * 64 * 2 * sizeof(float);
    float* ws = (float*)d_ws;

    if (ws_size >= needed) {
        float* wsP = ws;
        float* wsC = ws + (size_t)NBLK * 64;
        router_kernel<<<NBLK, 512, 0, stream>>>(tokens, W, out, wsP, wsC, 0);
        aux_kernel<<<1, 256, 0, stream>>>(wsP, wsC, out, NBLK);
    } else {
        hipMemsetAsync(d_ws, 0, 128 * sizeof(float), stream);
        float* wsP = ws;
        float* wsC = ws + 64;
        router_kernel<<<NBLK, 512, 0, stream>>>(tokens, W, out, wsP, wsC, 1);
        aux_kernel<<<1, 256, 0, stream>>>(wsP, wsC, out, 1);
    }
}

// Round 3
// 189.342 us; speedup vs baseline: 2.0829x; 2.0829x over previous
//
#include <hip/hip_runtime.h>
#include <hip/hip_bf16.h>

#define T_TOKENS 16384
#define HIDDEN   2048
#define NEXP     64
#define TOPK     8
#define TOPKG    4
#define RSCALE   2.5f

#define TOKB     64                   // tokens per block (lane = token)
#define NBLK     (T_TOKENS / TOKB)    // 256 blocks = 1 per CU
#define NWAVE    8                    // wave w owns experts w*8..w*8+7
#define EPW      (NEXP / NWAVE)       // 8 experts per wave
#define KC       128                  // k-chunk (floats) staged per barrier
#define NCH      (HIDDEN / KC)        // 16 chunks
#define TSTR     132                  // token row stride in LDS (132 mod 32 == 4 -> conflict-free b128)
#define ESTR     68                   // logits row stride (68 mod 32 == 4)

// ---------------------------------------------------------------------------
// lane = token; wave = 8-expert slice; full K accumulated in acc[8].
// W operand: wave-uniform address -> s_load (scalar pipe), free SGPR src in FMA.
// Token operand: one ds_read_b128 feeds 32 FMAs.
// ---------------------------------------------------------------------------
__global__ __launch_bounds__(512)
void router_kernel(const float* __restrict__ tokens,
                   const float* __restrict__ W,
                   float* __restrict__ out,
                   float* __restrict__ wsP,
                   float* __restrict__ wsC,
                   int atomicMode)
{
    __shared__ float tokLds[TOKB * TSTR];   // 33 KB; reused for logits in epilogue
    __shared__ float redP[NWAVE][NEXP];
    __shared__ float redC[NWAVE][NEXP];

    const int tid  = threadIdx.x;
    const int lane = tid & 63;
    const int wv   = __builtin_amdgcn_readfirstlane(tid >> 6);
    const int base = blockIdx.x * TOKB;

    float acc[EPW];
    #pragma unroll
    for (int e = 0; e < EPW; ++e) acc[e] = 0.f;

    // wave-uniform W base for this wave's 8 experts
    const float* Wv = W + (size_t)wv * EPW * HIDDEN;

    for (int c = 0; c < NCH; ++c) {
        // stage 64 tokens x 128 floats: 2048 float4 over 512 threads
        #pragma unroll
        for (int it = 0; it < 4; ++it) {
            int i  = it * 512 + tid;
            int t  = i >> 5;
            int j4 = i & 31;
            *(float4*)&tokLds[t * TSTR + j4 * 4] =
                *(const float4*)&tokens[(size_t)(base + t) * HIDDEN + c * KC + j4 * 4];
        }
        __syncthreads();

        #pragma unroll 2
        for (int k4 = 0; k4 < KC / 4; ++k4) {
            float4 t4 = *(const float4*)&tokLds[lane * TSTR + k4 * 4];
            #pragma unroll
            for (int e = 0; e < EPW; ++e) {
                const float* wp = &Wv[(size_t)e * HIDDEN + c * KC + k4 * 4]; // uniform -> s_load
                acc[e] = fmaf(wp[0], t4.x, acc[e]);
                acc[e] = fmaf(wp[1], t4.y, acc[e]);
                acc[e] = fmaf(wp[2], t4.z, acc[e]);
                acc[e] = fmaf(wp[3], t4.w, acc[e]);
            }
        }
        __syncthreads();
    }

    // ---- gather logits: token row = lane, experts wv*8..wv*8+7 ----
    {
        float4 a0 = make_float4(acc[0], acc[1], acc[2], acc[3]);
        float4 a1 = make_float4(acc[4], acc[5], acc[6], acc[7]);
        *(float4*)&tokLds[lane * ESTR + wv * EPW]     = a0;
        *(float4*)&tokLds[lane * ESTR + wv * EPW + 4] = a1;
    }
    __syncthreads();

    // ---- epilogue: wave wv handles tokens wv*8..wv*8+7, lane = expert ----
    float psum = 0.f;
    float cnt  = 0.f;

    #pragma unroll
    for (int tt = 0; tt < 8; ++tt) {
        const int tloc  = wv * 8 + tt;
        const int token = base + tloc;
        float logit = tokLds[tloc * ESTR + lane];
        float s = 1.f / (1.f + expf(-logit));   // sigmoid, lane = expert

        // group max over 8 consecutive lanes
        float gm = s;
        gm = fmaxf(gm, __shfl_xor(gm, 1));
        gm = fmaxf(gm, __shfl_xor(gm, 2));
        gm = fmaxf(gm, __shfl_xor(gm, 4));

        // rank my group among the 8 group maxima (tie-break: lower index)
        const int myg = lane >> 3;
        int rank = 0;
        #pragma unroll
        for (int g = 0; g < 8; ++g) {
            float gs = __shfl(gm, g * 8);
            rank += (gs > gm) || (gs == gm && g < myg);
        }
        float routed = (rank < TOPKG) ? s : 0.f;

        // full-row score sum (aux normalization)
        float ssum = s;
        #pragma unroll
        for (int off = 1; off < 64; off <<= 1) ssum += __shfl_xor(ssum, off);
        psum += s / fmaxf(ssum, 1e-9f);

        // sequential top-8 wave argmax (value desc, lower index on ties)
        float v = routed;
        int   idx = lane;
        float denom = 0.f;
        float myv = 0.f;
        int   myi = 0;
        #pragma unroll
        for (int k = 0; k < TOPK; ++k) {
            float bv = v;
            int   bi = idx;
            #pragma unroll
            for (int off = 1; off < 64; off <<= 1) {
                float ov = __shfl_xor(bv, off);
                int   oi = __shfl_xor(bi, off);
                if (ov > bv || (ov == bv && oi < bi)) { bv = ov; bi = oi; }
            }
            denom += bv;
            if (lane == k) { myv = bv; myi = bi; }
            if (lane == bi) { v = -1.f; cnt += 1.f; }
        }
        float wscale = RSCALE / fmaxf(denom, 1e-9f);
        if (lane < TOPK) {
            out[(size_t)token * TOPK + lane] = (float)myi;
            out[(size_t)T_TOKENS * TOPK + (size_t)token * TOPK + lane] = myv * wscale;
        }
    }

    // ---- block-level reduction of aux stats ----
    redP[wv][lane] = psum;
    redC[wv][lane] = cnt;
    __syncthreads();
    if (tid < 64) {
        float p = 0.f, c = 0.f;
        #pragma unroll
        for (int w = 0; w < NWAVE; ++w) { p += redP[w][tid]; c += redC[w][tid]; }
        if (atomicMode) {
            atomicAdd(&wsP[tid], p);
            atomicAdd(&wsC[tid], c);
        } else {
            wsP[(size_t)blockIdx.x * 64 + tid] = p;
            wsC[(size_t)blockIdx.x * 64 + tid] = c;
        }
    }
}

// ---------------------------------------------------------------------------
// Kernel 2: reduce per-block stats -> aux loss scalar at out[T*K*2]
// ---------------------------------------------------------------------------
__global__ __launch_bounds__(256)
void aux_kernel(const float* __restrict__ wsP,
                const float* __restrict__ wsC,
                float* __restrict__ out, int nblk)
{
    __shared__ float sP[256];
    __shared__ float sC[256];
    const int tid  = threadIdx.x;
    const int e    = tid & 63;
    const int part = tid >> 6;
    float p = 0.f, c = 0.f;
    for (int b = part; b < nblk; b += 4) {
        p += wsP[(size_t)b * 64 + e];
        c += wsC[(size_t)b * 64 + e];
    }
    sP[tid] = p; sC[tid] = c;
    __syncthreads();
    if (tid < 64) {
        p = sP[tid] + sP[tid + 64] + sP[tid + 128] + sP[tid + 192];
        c = sC[tid] + sC[tid + 64] + sC[tid + 128] + sC[tid + 192];
        float val = (c * (1.f / ((float)T_TOKENS * (float)TOPK)))
                  * (p * (1.f / (float)T_TOKENS));
        #pragma unroll
        for (int off = 1; off < 64; off <<= 1) val += __shfl_xor(val, off);
        if (tid == 0) out[(size_t)T_TOKENS * TOPK * 2] = val * (float)NEXP;
    }
}

extern "C" void kernel_launch(void* const* d_in, const int* in_sizes, int n_in,
                              void* d_out, int out_size, void* d_ws, size_t ws_size,
                              hipStream_t stream)
{
    const float* tokens = (const float*)d_in[0];
    const float* W      = (const float*)d_in[1];
    float* out = (float*)d_out;

    const size_t needed = (size_t)NBLK * 64 * 2 * sizeof(float);
    float* ws = (float*)d_ws;

    if (ws_size >= needed) {
        float* wsP = ws;
        float* wsC = ws + (size_t)NBLK * 64;
        router_kernel<<<NBLK, 512, 0, stream>>>(tokens, W, out, wsP, wsC, 0);
        aux_kernel<<<1, 256, 0, stream>>>(wsP, wsC, out, NBLK);
    } else {
        hipMemsetAsync(d_ws, 0, 128 * sizeof(float), stream);
        float* wsP = ws;
        float* wsC = ws + 64;
        router_kernel<<<NBLK, 512, 0, stream>>>(tokens, W, out, wsP, wsC, 1);
        aux_kernel<<<1, 256, 0, stream>>>(wsP, wsC, out, 1);
    }
}